// Round 9
// baseline (77.344 us; speedup 1.0000x reference)
//
#include <hip/hip_runtime.h>

// SGNN projection, round 9: force single v_mad_u64_u32 for the 62-bit product.
//
// Math (M = 2^31-1 Mersenne, HALF = 2^30-1):
//   centered(v) = ((v + HALF) mod M) - HALF  ->  p2 = sig*seed + HALF (ONE v_mad_u64_u32,
//   forced via inline asm; theory: compiler lowers the C expression to
//   mul_lo + mul_hi + 64-bit add, ~2x the cost — this is the round's single variable).
//   Fold: s = (p2>>31) + (p2 & M) <= 2^32-4 < 2M ALWAYS (sig,seed <= 2^31-2), so
//   residue = s - M*[s>=M] exactly. centered partial = sum(s) - M*q - n*HALF, exact int64.
//   Pad-zero slots (sig=0) give s = HALF exactly, removed by the n*HALF term.
//
// Per-element: v_mad_u64_u32 + alignbit + and + add + cmp + addc + add_co + addc = 8 inst.

#define M31    2147483647u   // 2^31 - 1
#define HALF_B 1073741823u   // 2^30 - 1

__global__ __launch_bounds__(64) void sgnn_prep_kernel(
    const int* __restrict__ sig,    // [3, B, 128]
    const int* __restrict__ mask,   // [3, B, 128]
    unsigned* __restrict__ msig,    // [3, B, 128] compacted, zero-padded to cnt4
    float* __restrict__ invc,       // [3, B] = 1/(max(cnt,1)*HALF)
    unsigned* __restrict__ cnt4)    // [3, B] = ceil(cnt/4)*4
{
    const int row = blockIdx.x;          // p*nbatch + b
    const int t   = threadIdx.x;         // one wave
    const int g0  = row * 128 + t;
    const int g1  = g0 + 64;
    const int mk0 = mask[g0], mk1 = mask[g1];
    const unsigned v0 = (unsigned)sig[g0], v1 = (unsigned)sig[g1];

    const unsigned long long b0 = __ballot(mk0 != 0);
    const unsigned long long b1 = __ballot(mk1 != 0);
    const unsigned long long lt = (1ULL << t) - 1ULL;
    const int c0   = __popcll(b0);
    const int cnt  = c0 + __popcll(b1);
    const int pos0 = __popcll(b0 & lt);
    const int pos1 = c0 + __popcll(b1 & lt);

    const unsigned base = (unsigned)row * 128u;
    if (mk0) msig[base + pos0] = v0;
    if (mk1) msig[base + pos1] = v1;

    const int c4 = (cnt + 3) & ~3;
    if (cnt + t < c4) msig[base + cnt + t] = 0u;   // zero-pad (<=3 slots)

    if (t == 0) {
        int c = (cnt < 1) ? 1 : cnt;
        invc[row] = 1.0f / ((float)c * 1073741823.0f);
        cnt4[row] = (unsigned)c4;
    }
}

__device__ __forceinline__ void acc_elem(unsigned v, unsigned seed,
                                         unsigned long long half64,
                                         unsigned long long& sum, unsigned& q) {
    unsigned long long p2;
    unsigned long long carry_dummy;
    // p2 = v * seed + HALF in ONE instruction (64-bit mad, quarter rate)
    asm("v_mad_u64_u32 %0, %1, %2, %3, %4"
        : "=v"(p2), "=s"(carry_dummy)
        : "v"(v), "v"(seed), "v"(half64));
    const unsigned lo = (unsigned)p2;
    const unsigned hi = (unsigned)(p2 >> 32);
    const unsigned s  = __builtin_amdgcn_alignbit(hi, lo, 31) + (lo & 0x7FFFFFFFu);
    q   += (s >= M31);
    sum += s;
}

__device__ __forceinline__ void acc4(uint4 a, unsigned seed, unsigned long long half64,
                                     unsigned long long& s0, unsigned long long& s1,
                                     unsigned& q0, unsigned& q1) {
    acc_elem(a.x, seed, half64, s0, q0); acc_elem(a.y, seed, half64, s1, q1);
    acc_elem(a.z, seed, half64, s0, q0); acc_elem(a.w, seed, half64, s1, q1);
}

__global__ __launch_bounds__(256, 4) void sgnn_main_kernel(
    const unsigned* __restrict__ msig,  // [3, B, 128] compacted
    const float* __restrict__ invc,     // [3, B]
    const unsigned* __restrict__ cnt4,  // [3, B]
    const int* __restrict__ seeds,      // [672]
    float* __restrict__ out,            // [B, 672] == flat[t]
    int nbatch)
{
    const unsigned t = blockIdx.x * 256u + threadIdx.x;  // [0, nbatch*672)
    // b = floor(t/672) = floor((t>>5)/21), exact for t < 2^21 via magic 99865 = ceil(2^21/21)
    const unsigned x = t >> 5;
    const unsigned b = (x * 99865u) >> 21;
    const unsigned h = t - 672u * b;
    const int p = (h < 112u) ? 0 : (h < 336u) ? 1 : 2;

    const unsigned row = (unsigned)(p * nbatch) + b;
    const unsigned* __restrict__ rp = msig + row * 128u;
    const unsigned seed = (unsigned)seeds[h];
    const unsigned n = cnt4[row];        // multiple of 4, may be 0
    const unsigned long long half64 = (unsigned long long)HALF_B;

    unsigned long long sum0 = 0, sum1 = 0;  // s < 2^32 each; <=128 elems < 2^39, exact
    unsigned q0 = 0, q1 = 0;

    unsigned mm = 0;
    const unsigned n16 = n & ~15u;
    for (; mm < n16; mm += 16) {
        const uint4 a = *(const uint4*)(rp + mm);
        const uint4 c = *(const uint4*)(rp + mm + 4);
        const uint4 d = *(const uint4*)(rp + mm + 8);
        const uint4 e = *(const uint4*)(rp + mm + 12);
        acc4(a, seed, half64, sum0, sum1, q0, q1);
        acc4(c, seed, half64, sum0, sum1, q0, q1);
        acc4(d, seed, half64, sum0, sum1, q0, q1);
        acc4(e, seed, half64, sum0, sum1, q0, q1);
    }
    for (; mm < n; mm += 4) {            // <=3 groups of 4
        const uint4 a = *(const uint4*)(rp + mm);
        acc4(a, seed, half64, sum0, sum1, q0, q1);
    }

    const long long centered = (long long)(sum0 + sum1)
                             - (long long)(q0 + q1) * 2147483647LL
                             - (long long)n * 1073741823LL;
    out[t] = (float)centered * invc[row];
}

extern "C" void kernel_launch(void* const* d_in, const int* in_sizes, int n_in,
                              void* d_out, int out_size, void* d_ws, size_t ws_size,
                              hipStream_t stream) {
    const int* sig   = (const int*)d_in[0];
    const int* mask  = (const int*)d_in[1];
    const int* seeds = (const int*)d_in[2];
    float* out = (float*)d_out;

    const int nbatch = in_sizes[0] / (3 * 128);         // 1024
    const int nrows  = 3 * nbatch;                      // 3072
    unsigned* msig = (unsigned*)d_ws;                                    // nrows*128 u32
    float*    invc = (float*)((char*)d_ws + (size_t)nrows * 128 * 4);    // nrows f32
    unsigned* c4   = (unsigned*)((char*)d_ws + (size_t)nrows * 132 * 4); // nrows u32

    sgnn_prep_kernel<<<dim3(nrows), dim3(64), 0, stream>>>(sig, mask, msig, invc, c4);
    const int total = nbatch * 672;                     // 688128 = 2688 * 256 exactly
    sgnn_main_kernel<<<dim3(total / 256), dim3(256), 0, stream>>>(msig, invc, c4, seeds, out, nbatch);
}

// Round 10
// 77.327 us; speedup vs baseline: 1.0002x; 1.0002x over previous
//
#include <hip/hip_runtime.h>

// SGNN projection, round 10: row-pure waves + SCALAR (SMEM) sig loads.
//
// Math (M = 2^31-1 Mersenne, HALF = 2^30-1):
//   centered(v) = ((v + HALF) mod M) - HALF  ->  p2 = sig*seed + HALF.
//   Fold: s = (p2>>31) + (p2 & M) <= 2^32-4 < 2M ALWAYS (sig,seed <= 2^31-2), so
//   residue = s - M*[s>=M] exactly. centered partial = sum(s) - M*q - n*HALF, exact int64.
//   Pad-zero slots (sig=0) give s = HALF exactly, removed by the n*HALF term.
//
// R10 hypothesis: the unexplained ~2x over the VALU issue floor is the VMEM path
// (24+ wave-uniform global_load_dwordx4 per wave threading vmcnt through the loop).
// Fix: make every wave row-pure (grid (3,B); 12 waves/row: p0->2, p1->4, p2->6,
// ~12.5% idle lanes) and force the row pointer scalar via readfirstlane, so the
// compacted sig words load through s_load into SGPRs - the hot loop becomes pure
// VALU (sig is the one legal SGPR operand of the mad), zero vmcnt inside.

#define M31    2147483647u   // 2^31 - 1
#define HALF_B 1073741823u   // 2^30 - 1

__global__ __launch_bounds__(64) void sgnn_prep_kernel(
    const int* __restrict__ sig,    // [3, B, 128]
    const int* __restrict__ mask,   // [3, B, 128]
    unsigned* __restrict__ msig,    // [3, B, 128] compacted, zero-padded to cnt4
    float* __restrict__ invc,       // [3, B] = 1/(max(cnt,1)*HALF)
    unsigned* __restrict__ cnt4)    // [3, B] = ceil(cnt/4)*4
{
    const int row = blockIdx.x;          // p*nbatch + b
    const int t   = threadIdx.x;         // one wave
    const int g0  = row * 128 + t;
    const int g1  = g0 + 64;
    const int mk0 = mask[g0], mk1 = mask[g1];
    const unsigned v0 = (unsigned)sig[g0], v1 = (unsigned)sig[g1];

    const unsigned long long b0 = __ballot(mk0 != 0);
    const unsigned long long b1 = __ballot(mk1 != 0);
    const unsigned long long lt = (1ULL << t) - 1ULL;
    const int c0   = __popcll(b0);
    const int cnt  = c0 + __popcll(b1);
    const int pos0 = __popcll(b0 & lt);
    const int pos1 = c0 + __popcll(b1 & lt);

    const unsigned base = (unsigned)row * 128u;
    if (mk0) msig[base + pos0] = v0;
    if (mk1) msig[base + pos1] = v1;

    const int c4 = (cnt + 3) & ~3;
    if (cnt + t < c4) msig[base + cnt + t] = 0u;   // zero-pad (<=3 slots)

    if (t == 0) {
        int c = (cnt < 1) ? 1 : cnt;
        invc[row] = 1.0f / ((float)c * 1073741823.0f);
        cnt4[row] = (unsigned)c4;
    }
}

__device__ __forceinline__ void acc_elem(unsigned sv /*wave-uniform (SGPR)*/,
                                         unsigned seed /*per-lane*/,
                                         unsigned long long& sum, unsigned& q) {
    const unsigned long long p2 =
        (unsigned long long)sv * (unsigned long long)seed + (unsigned long long)HALF_B;
    const unsigned lo = (unsigned)p2;
    const unsigned hi = (unsigned)(p2 >> 32);
    const unsigned s  = __builtin_amdgcn_alignbit(hi, lo, 31) + (lo & 0x7FFFFFFFu);
    q   += (s >= M31);
    sum += s;
}

__global__ __launch_bounds__(256, 4) void sgnn_main_kernel(
    const unsigned* __restrict__ msig,  // [3, B, 128] compacted
    const float* __restrict__ invc,     // [3, B]
    const unsigned* __restrict__ cnt4,  // [3, B]
    const int* __restrict__ seeds,      // [672]
    float* __restrict__ out,            // [B, 672]
    int nbatch)
{
    // Row-pure wave map: W = blockIdx.x*4 + wave in [0,12) for batch row b = blockIdx.y.
    //   W in [0,2):  p=0, h0 = W*64,            hmax = 112
    //   W in [2,6):  p=1, h0 = 112 + (W-2)*64,  hmax = 336
    //   W in [6,12): p=2, h0 = 336 + (W-6)*64,  hmax = 672
    const unsigned tid  = threadIdx.x;
    const unsigned lane = tid & 63u;
    const unsigned W    = blockIdx.x * 4u + (tid >> 6);
    const unsigned b    = blockIdx.y;

    unsigned p, h0, hmax;
    if (W < 2u)      { p = 0; h0 = W * 64u;              hmax = 112u; }
    else if (W < 6u) { p = 1; h0 = 112u + (W - 2u) * 64u; hmax = 336u; }
    else             { p = 2; h0 = 336u + (W - 6u) * 64u; hmax = 672u; }

    const unsigned h     = h0 + lane;
    const bool     valid = (h < hmax);
    const unsigned h_c   = valid ? h : (hmax - 1u);

    // Force the row pointer scalar: p is wave-uniform by construction, but the
    // compiler can't prove it (derived from threadIdx). readfirstlane -> SGPR,
    // so the sig loads below become s_load (SMEM pipe, no vmcnt in the loop).
    const unsigned row_u = __builtin_amdgcn_readfirstlane(p * (unsigned)nbatch + b);
    const unsigned* __restrict__ rp = msig + (size_t)row_u * 128u;
    const unsigned n = cnt4[row_u];      // uniform -> s_load; multiple of 4, may be 0
    const unsigned seed = (unsigned)seeds[h_c];

    unsigned long long sum0 = 0, sum1 = 0;  // s < 2^32 each; <=128 elems < 2^39, exact
    unsigned q0 = 0, q1 = 0;

    unsigned mm = 0;
    const unsigned n16 = n & ~15u;
    for (; mm < n16; mm += 16) {
        #pragma unroll
        for (unsigned jj = 0; jj < 16; jj += 2) {
            acc_elem(rp[mm + jj],     seed, sum0, q0);
            acc_elem(rp[mm + jj + 1], seed, sum1, q1);
        }
    }
    for (; mm < n; mm += 4) {            // <=3 groups of 4, trip count wave-uniform
        #pragma unroll
        for (unsigned jj = 0; jj < 4; jj += 2) {
            acc_elem(rp[mm + jj],     seed, sum0, q0);
            acc_elem(rp[mm + jj + 1], seed, sum1, q1);
        }
    }

    if (valid) {
        const long long centered = (long long)(sum0 + sum1)
                                 - (long long)(q0 + q1) * 2147483647LL
                                 - (long long)n * 1073741823LL;
        out[b * 672u + h] = (float)centered * invc[row_u];
    }
}

extern "C" void kernel_launch(void* const* d_in, const int* in_sizes, int n_in,
                              void* d_out, int out_size, void* d_ws, size_t ws_size,
                              hipStream_t stream) {
    const int* sig   = (const int*)d_in[0];
    const int* mask  = (const int*)d_in[1];
    const int* seeds = (const int*)d_in[2];
    float* out = (float*)d_out;

    const int nbatch = in_sizes[0] / (3 * 128);         // 1024
    const int nrows  = 3 * nbatch;                      // 3072
    unsigned* msig = (unsigned*)d_ws;                                    // nrows*128 u32
    float*    invc = (float*)((char*)d_ws + (size_t)nrows * 128 * 4);    // nrows f32
    unsigned* c4   = (unsigned*)((char*)d_ws + (size_t)nrows * 132 * 4); // nrows u32

    sgnn_prep_kernel<<<dim3(nrows), dim3(64), 0, stream>>>(sig, mask, msig, invc, c4);
    // 3 blocks (12 waves) per batch row, all waves row-pure
    sgnn_main_kernel<<<dim3(3, nbatch), dim3(256), 0, stream>>>(msig, invc, c4, seeds, out, nbatch);
}

// Round 11
// 73.701 us; speedup vs baseline: 1.0494x; 1.0492x over previous
//
#include <hip/hip_runtime.h>

// SGNN projection, round 11: single fused kernel, LDS-compacted rows.
//
// Math (M = 2^31-1 Mersenne, HALF = 2^30-1):
//   centered(v) = ((v + HALF) mod M) - HALF  ->  p2 = v*seed + HALF.
//   Fold: s = (p2>>31) + (p2 & M) <= 2^32-4 < 2M ALWAYS (v,seed <= 2^31-2).
//   Exact residue WITHOUT quotient bookkeeping: r = min_u32(s, s - M)
//     (s < M: s-M wraps huge, min = s; s >= M: s-M <= 2^31-1, min = s-M). EXACT.
//   centered sum = sum(r) - n*HALF (pad zeros give r = HALF, removed by n*HALF).
//
// Structure: one block per batch row b (768 thr = 12 waves). Waves 0-2
// ballot-compact rows 0-2 (sig masked, packed front, zero-pad to cnt4) into
// LDS; barrier; 12 row-pure waves (2/4/6 for p0/p1/p2, 64 seeds each, 12.5%
// lanes idle at partition edges) consume via wave-uniform ds_read_b128
// (broadcast). One dispatch total: saves prep dispatch + gap + msig RT.

#define M31    2147483647u   // 2^31 - 1
#define HALF_B 1073741823u   // 2^30 - 1

__global__ __launch_bounds__(768) void sgnn_fused_kernel(
    const int* __restrict__ sig,    // [3, B, 128]
    const int* __restrict__ mask,   // [3, B, 128]
    const int* __restrict__ seeds,  // [672]
    float* __restrict__ out,        // [B, 672]
    int nbatch)
{
    __shared__ unsigned srow[3][128];  // compacted, zero-padded to cnt4
    __shared__ float    sinv[3];       // 1/(max(cnt,1)*HALF)
    __shared__ unsigned sn[3];         // cnt4 = ceil(cnt/4)*4

    const unsigned tid  = threadIdx.x;
    const unsigned lane = tid & 63u;
    const unsigned W    = tid >> 6;    // wave id in [0,12)
    const unsigned b    = blockIdx.x;

    // ---- Stage: waves 0-2 compact row W of batch b into LDS ----
    if (W < 3u) {
        const unsigned rowg = W * (unsigned)nbatch + b;
        const unsigned g0 = rowg * 128u + lane;
        const unsigned g1 = g0 + 64u;
        const int mk0 = mask[g0], mk1 = mask[g1];
        const unsigned v0 = (unsigned)sig[g0], v1 = (unsigned)sig[g1];

        const unsigned long long b0 = __ballot(mk0 != 0);
        const unsigned long long b1 = __ballot(mk1 != 0);
        const unsigned long long lt = (1ULL << lane) - 1ULL;
        const int c0   = __popcll(b0);
        const int cnt  = c0 + __popcll(b1);
        const int pos0 = __popcll(b0 & lt);
        const int pos1 = c0 + __popcll(b1 & lt);

        if (mk0) srow[W][pos0] = v0;
        if (mk1) srow[W][pos1] = v1;

        const int c4 = (cnt + 3) & ~3;
        if ((int)(cnt + lane) < c4) srow[W][cnt + lane] = 0u;  // <=3 pad slots

        if (lane == 0) {
            int c = (cnt < 1) ? 1 : cnt;
            sinv[W] = 1.0f / ((float)c * 1073741823.0f);
            sn[W]   = (unsigned)c4;
        }
    }
    __syncthreads();

    // ---- Compute: 12 row-pure waves ----
    //   W in [0,2):  p=0, h0 = W*64,             hmax = 112
    //   W in [2,6):  p=1, h0 = 112 + (W-2)*64,   hmax = 336
    //   W in [6,12): p=2, h0 = 336 + (W-6)*64,   hmax = 672
    unsigned p, h0, hmax;
    if (W < 2u)      { p = 0; h0 = W * 64u;               hmax = 112u; }
    else if (W < 6u) { p = 1; h0 = 112u + (W - 2u) * 64u; hmax = 336u; }
    else             { p = 2; h0 = 336u + (W - 6u) * 64u; hmax = 672u; }

    const unsigned h     = h0 + lane;
    const bool     valid = (h < hmax);
    const unsigned h_c   = valid ? h : (hmax - 1u);

    const unsigned long long seed = (unsigned long long)(unsigned)seeds[h_c];
    const unsigned n = sn[p];            // wave-uniform, multiple of 4, may be 0

    unsigned long long sum0 = 0, sum1 = 0;  // r <= M-1; <=128 elems < 2^38, exact
    unsigned mm = 0;
    const unsigned n8 = n & ~7u;
    for (; mm < n8; mm += 8) {
        const uint4 a = *(const uint4*)&srow[p][mm];      // ds_read_b128, broadcast
        const uint4 c = *(const uint4*)&srow[p][mm + 4];
        {
            const unsigned long long p2 = (unsigned long long)a.x * seed + HALF_B;
            const unsigned s = __builtin_amdgcn_alignbit((unsigned)(p2 >> 32), (unsigned)p2, 31)
                             + ((unsigned)p2 & 0x7FFFFFFFu);
            sum0 += min(s, s - M31);
        }
        {
            const unsigned long long p2 = (unsigned long long)a.y * seed + HALF_B;
            const unsigned s = __builtin_amdgcn_alignbit((unsigned)(p2 >> 32), (unsigned)p2, 31)
                             + ((unsigned)p2 & 0x7FFFFFFFu);
            sum1 += min(s, s - M31);
        }
        {
            const unsigned long long p2 = (unsigned long long)a.z * seed + HALF_B;
            const unsigned s = __builtin_amdgcn_alignbit((unsigned)(p2 >> 32), (unsigned)p2, 31)
                             + ((unsigned)p2 & 0x7FFFFFFFu);
            sum0 += min(s, s - M31);
        }
        {
            const unsigned long long p2 = (unsigned long long)a.w * seed + HALF_B;
            const unsigned s = __builtin_amdgcn_alignbit((unsigned)(p2 >> 32), (unsigned)p2, 31)
                             + ((unsigned)p2 & 0x7FFFFFFFu);
            sum1 += min(s, s - M31);
        }
        {
            const unsigned long long p2 = (unsigned long long)c.x * seed + HALF_B;
            const unsigned s = __builtin_amdgcn_alignbit((unsigned)(p2 >> 32), (unsigned)p2, 31)
                             + ((unsigned)p2 & 0x7FFFFFFFu);
            sum0 += min(s, s - M31);
        }
        {
            const unsigned long long p2 = (unsigned long long)c.y * seed + HALF_B;
            const unsigned s = __builtin_amdgcn_alignbit((unsigned)(p2 >> 32), (unsigned)p2, 31)
                             + ((unsigned)p2 & 0x7FFFFFFFu);
            sum1 += min(s, s - M31);
        }
        {
            const unsigned long long p2 = (unsigned long long)c.z * seed + HALF_B;
            const unsigned s = __builtin_amdgcn_alignbit((unsigned)(p2 >> 32), (unsigned)p2, 31)
                             + ((unsigned)p2 & 0x7FFFFFFFu);
            sum0 += min(s, s - M31);
        }
        {
            const unsigned long long p2 = (unsigned long long)c.w * seed + HALF_B;
            const unsigned s = __builtin_amdgcn_alignbit((unsigned)(p2 >> 32), (unsigned)p2, 31)
                             + ((unsigned)p2 & 0x7FFFFFFFu);
            sum1 += min(s, s - M31);
        }
    }
    if (mm < n) {                        // one step-4 tail (n multiple of 4)
        const uint4 a = *(const uint4*)&srow[p][mm];
        {
            const unsigned long long p2 = (unsigned long long)a.x * seed + HALF_B;
            const unsigned s = __builtin_amdgcn_alignbit((unsigned)(p2 >> 32), (unsigned)p2, 31)
                             + ((unsigned)p2 & 0x7FFFFFFFu);
            sum0 += min(s, s - M31);
        }
        {
            const unsigned long long p2 = (unsigned long long)a.y * seed + HALF_B;
            const unsigned s = __builtin_amdgcn_alignbit((unsigned)(p2 >> 32), (unsigned)p2, 31)
                             + ((unsigned)p2 & 0x7FFFFFFFu);
            sum1 += min(s, s - M31);
        }
        {
            const unsigned long long p2 = (unsigned long long)a.z * seed + HALF_B;
            const unsigned s = __builtin_amdgcn_alignbit((unsigned)(p2 >> 32), (unsigned)p2, 31)
                             + ((unsigned)p2 & 0x7FFFFFFFu);
            sum0 += min(s, s - M31);
        }
        {
            const unsigned long long p2 = (unsigned long long)a.w * seed + HALF_B;
            const unsigned s = __builtin_amdgcn_alignbit((unsigned)(p2 >> 32), (unsigned)p2, 31)
                             + ((unsigned)p2 & 0x7FFFFFFFu);
            sum1 += min(s, s - M31);
        }
    }

    if (valid) {
        const long long centered = (long long)(sum0 + sum1)
                                 - (long long)n * 1073741823LL;
        out[b * 672u + h] = (float)centered * sinv[p];
    }
}

extern "C" void kernel_launch(void* const* d_in, const int* in_sizes, int n_in,
                              void* d_out, int out_size, void* d_ws, size_t ws_size,
                              hipStream_t stream) {
    const int* sig   = (const int*)d_in[0];
    const int* mask  = (const int*)d_in[1];
    const int* seeds = (const int*)d_in[2];
    float* out = (float*)d_out;

    const int nbatch = in_sizes[0] / (3 * 128);  // 1024
    sgnn_fused_kernel<<<dim3(nbatch), dim3(768), 0, stream>>>(sig, mask, seeds, out, nbatch);
}

// Round 12
// 73.329 us; speedup vs baseline: 1.0547x; 1.0051x over previous
//
#include <hip/hip_runtime.h>

// SGNN projection, round 12: fused, 11-wave flat map (4.5% idle vs 12.5%) + pair-sum.
//
// Math (M = 2^31-1 Mersenne, HALF = 2^30-1):
//   centered(v) = ((v + HALF) mod M) - HALF  ->  p2 = v*seed + HALF.
//   Fold: s = (p2>>31) + (p2 & M) <= 2^32-4 < 2M ALWAYS (v,seed <= 2^31-2).
//   Residue: r = min_u32(s, s - M) -- exact branchless mod.
//   Zero slots give r = HALF exactly, so summing N8 slots (compacted row
//   zero-filled to 128) and subtracting N8*HALF equals the exact centered sum
//   over the cnt real elements, for ANY N8 in [cnt, 128]. This lets straddling
//   waves use a wave-uniform trip count N8 = roundup8(max(cnt_plo, cnt_phi)).
//   Pair-sum: r <= 2^31-2, so r_a + r_b fits u32 exactly -> halves the 64-bit
//   accumulate traffic.
//
// Structure: one block per batch row (704 thr = 11 waves). Waves 0-2 ballot-
// compact rows 0-2 into LDS (front-packed, zero-filled to 128 -- disjoint
// ranges, no race); barrier; h = tid (flat), per-lane p, per-lane LDS row
// (<=2-way bank aliasing = free). One dispatch, no workspace.

#define M31    2147483647u   // 2^31 - 1
#define HALF_B 1073741823u   // 2^30 - 1

__device__ __forceinline__ unsigned relem(unsigned v, unsigned long long seed) {
    const unsigned long long p2 = (unsigned long long)v * seed + (unsigned long long)HALF_B;
    const unsigned lo = (unsigned)p2;
    const unsigned hi = (unsigned)(p2 >> 32);
    const unsigned s  = __builtin_amdgcn_alignbit(hi, lo, 31) + (lo & 0x7FFFFFFFu);
    return min(s, s - M31);              // exact (v*seed+HALF) mod M
}

__global__ __launch_bounds__(704) void sgnn_fused_kernel(
    const int* __restrict__ sig,    // [3, B, 128]
    const int* __restrict__ mask,   // [3, B, 128]
    const int* __restrict__ seeds,  // [672]
    float* __restrict__ out,        // [B, 672]
    int nbatch)
{
    __shared__ unsigned srow[3][128];  // compacted front, zero-filled to 128
    __shared__ float    sinv[3];       // 1/(max(cnt,1)*HALF)
    __shared__ unsigned scnt[3];       // raw valid count

    const unsigned tid  = threadIdx.x;
    const unsigned lane = tid & 63u;
    const unsigned W    = tid >> 6;    // wave id in [0,11)
    const unsigned b    = blockIdx.x;

    // ---- Stage: waves 0-2 compact row W of batch b into LDS ----
    if (W < 3u) {
        const unsigned rowg = W * (unsigned)nbatch + b;
        const unsigned g0 = rowg * 128u + lane;
        const unsigned g1 = g0 + 64u;
        const int mk0 = mask[g0], mk1 = mask[g1];
        const unsigned v0 = (unsigned)sig[g0], v1 = (unsigned)sig[g1];

        const unsigned long long b0 = __ballot(mk0 != 0);
        const unsigned long long b1 = __ballot(mk1 != 0);
        const unsigned long long lt = (1ULL << lane) - 1ULL;
        const unsigned c0   = (unsigned)__popcll(b0);
        const unsigned cnt  = c0 + (unsigned)__popcll(b1);
        const unsigned pos0 = (unsigned)__popcll(b0 & lt);
        const unsigned pos1 = c0 + (unsigned)__popcll(b1 & lt);

        if (mk0) srow[W][pos0] = v0;
        if (mk1) srow[W][pos1] = v1;
        // zero-fill [cnt, 128) -- disjoint from compacted [0, cnt), no race
        if (cnt + lane < 128u)       srow[W][cnt + lane]       = 0u;
        if (cnt + 64u + lane < 128u) srow[W][cnt + 64u + lane] = 0u;

        if (lane == 0) {
            unsigned c = (cnt < 1u) ? 1u : cnt;
            sinv[W] = 1.0f / ((float)c * 1073741823.0f);
            scnt[W] = cnt;
        }
    }
    __syncthreads();

    // ---- Compute: flat h = tid, 672 outputs over 11 waves ----
    const unsigned h     = tid;
    const bool     valid = (h < 672u);
    const unsigned h_c   = valid ? h : 671u;
    const unsigned p     = (h_c < 112u) ? 0u : (h_c < 336u) ? 1u : 2u;

    // wave-uniform trip count: max cnt over the <=2 partitions this wave spans
    const unsigned wh0 = tid & ~63u;                 // wave's first h
    const unsigned wh1 = (wh0 + 63u < 671u) ? wh0 + 63u : 671u;
    const unsigned plo = (wh0 < 112u) ? 0u : (wh0 < 336u) ? 1u : 2u;
    const unsigned phi = (wh1 < 112u) ? 0u : (wh1 < 336u) ? 1u : 2u;
    unsigned nmax = max(scnt[plo], scnt[phi]);
    nmax = (nmax + 7u) & ~7u;                        // step-8 loop, pads exact
    nmax = __builtin_amdgcn_readfirstlane(nmax);     // -> SGPR loop bound

    const unsigned long long seed = (unsigned long long)(unsigned)seeds[h_c];
    const unsigned* __restrict__ rp = srow[p];       // per-lane row (<=2 distinct)

    unsigned long long sum0 = 0, sum1 = 0;           // pair-sums: <=64 adds of <2^32, exact
    for (unsigned mm = 0; mm < nmax; mm += 8) {
        const uint4 a = *(const uint4*)&rp[mm];      // ds_read_b128
        const uint4 c = *(const uint4*)&rp[mm + 4];
        sum0 += (unsigned long long)(relem(a.x, seed) + relem(a.y, seed));  // u32 pair: exact
        sum1 += (unsigned long long)(relem(a.z, seed) + relem(a.w, seed));
        sum0 += (unsigned long long)(relem(c.x, seed) + relem(c.y, seed));
        sum1 += (unsigned long long)(relem(c.z, seed) + relem(c.w, seed));
    }

    if (valid) {
        const long long centered = (long long)(sum0 + sum1)
                                 - (long long)nmax * 1073741823LL;
        out[b * 672u + h] = (float)centered * sinv[p];
    }
}

extern "C" void kernel_launch(void* const* d_in, const int* in_sizes, int n_in,
                              void* d_out, int out_size, void* d_ws, size_t ws_size,
                              hipStream_t stream) {
    const int* sig   = (const int*)d_in[0];
    const int* mask  = (const int*)d_in[1];
    const int* seeds = (const int*)d_in[2];
    float* out = (float*)d_out;

    const int nbatch = in_sizes[0] / (3 * 128);  // 1024
    sgnn_fused_kernel<<<dim3(nbatch), dim3(704), 0, stream>>>(sig, mask, seeds, out, nbatch);
}